// Round 2
// baseline (58.210 us; speedup 1.0000x reference)
//
#include <hip/hip_runtime.h>

// Problem constants (from reference setup_inputs): B=4, N=2048, d=3.
#define BATCH 4
#define NPTS  2048
#define BLK   1024   // one block total: 4 batch-groups x 256 threads
#define TPB   256    // threads per batch-group
#define PPT   (NPTS / TPB)   // 8 points per thread

// acc layout (48 floats):
//  [0:3)   sx     sum x
//  [3:6)   sy     sum y
//  [6:12)  sxx    sum x_i x_j (sym6)
//  [12:18) syy    sum y_i y_j (sym6)
//  [18:27) sxy    sum x_i y_j (full 9)
//  [27:33) A      sum Rx Rx^T (sym6)
//  [33:39) Bm     sum Ry Ry^T (sym6)
//  [39:48) C      sum Rx Ry^T (full 9)
#define NACC 48

__global__ __launch_bounds__(BLK)
void fape_onepass_kernel(const float* __restrict__ x,
                         const float* __restrict__ Rx,
                         const float* __restrict__ y,
                         const float* __restrict__ Ry,
                         float* __restrict__ out)
{
    const int tid = threadIdx.x;
    const int b   = tid >> 8;     // batch group 0..3
    const int u   = tid & 255;    // index within batch group

    const float* __restrict__ xb  = x  + (size_t)b * NPTS * 3;
    const float* __restrict__ yb  = y  + (size_t)b * NPTS * 3;
    const float* __restrict__ rxb = Rx + (size_t)b * NPTS * 9;
    const float* __restrict__ ryb = Ry + (size_t)b * NPTS * 9;

    const int pi[6] = {0, 1, 2, 0, 0, 1};
    const int pj[6] = {0, 1, 2, 1, 2, 2};

    float acc[NACC];
#pragma unroll
    for (int q = 0; q < NACC; ++q) acc[q] = 0.f;

#pragma unroll
    for (int g = 0; g < PPT; ++g) {
        const int n = g * TPB + u;   // lane-consecutive points -> contiguous footprint
        float xv[3], yv[3], rx[9], ry[9];
#pragma unroll
        for (int i = 0; i < 3; ++i) { xv[i] = xb[n * 3 + i]; yv[i] = yb[n * 3 + i]; }
#pragma unroll
        for (int i = 0; i < 9; ++i) { rx[i] = rxb[n * 9 + i]; ry[i] = ryb[n * 9 + i]; }

#pragma unroll
        for (int i = 0; i < 3; ++i) { acc[0 + i] += xv[i]; acc[3 + i] += yv[i]; }

#pragma unroll
        for (int p = 0; p < 6; ++p) {
            const int i = pi[p], j = pj[p];
            acc[6  + p] += xv[i] * xv[j];
            acc[12 + p] += yv[i] * yv[j];
            float a = 0.f, bb = 0.f;
#pragma unroll
            for (int m = 0; m < 3; ++m) {
                a  += rx[i * 3 + m] * rx[j * 3 + m];
                bb += ry[i * 3 + m] * ry[j * 3 + m];
            }
            acc[27 + p] += a;
            acc[33 + p] += bb;
        }

#pragma unroll
        for (int i = 0; i < 3; ++i) {
#pragma unroll
            for (int j = 0; j < 3; ++j) {
                acc[18 + i * 3 + j] += xv[i] * yv[j];
                float c = 0.f;
#pragma unroll
                for (int m = 0; m < 3; ++m) c += rx[i * 3 + m] * ry[j * 3 + m];
                acc[39 + i * 3 + j] += c;
            }
        }
    }

    // wave-64 butterfly-free shuffle reduction
#pragma unroll
    for (int off = 32; off > 0; off >>= 1) {
#pragma unroll
        for (int q = 0; q < NACC; ++q) acc[q] += __shfl_down(acc[q], off, 64);
    }

    // cross-wave reduction: 16 waves total, 4 per batch group
    __shared__ float red[BLK / 64][NACC];
    const int wave = tid >> 6, lane = tid & 63;
    if (lane == 0) {
#pragma unroll
        for (int q = 0; q < NACC; ++q) red[wave][q] = acc[q];
    }
    __syncthreads();

    __shared__ float fin[BATCH][NACC];
    if (tid < BATCH * NACC) {
        const int bb = tid / NACC, q = tid % NACC;
        float s = 0.f;
#pragma unroll
        for (int k = 0; k < 4; ++k) s += red[bb * 4 + k][q];
        fin[bb][q] = s;
    }
    __syncthreads();

    __shared__ double dots[BATCH];
    if (tid < BATCH) {
        const float* f = fin[tid];
        const double Ninv = 1.0 / (double)NPTS;
        double sx[3], sy[3];
        for (int i = 0; i < 3; ++i) { sx[i] = f[0 + i]; sy[i] = f[3 + i]; }

        double Sx[6], Sy[6], Sxy[9];
        for (int p = 0; p < 6; ++p) {
            const int i = pi[p], j = pj[p];
            Sx[p] = (double)f[6  + p] - sx[i] * sx[j] * Ninv;
            Sy[p] = (double)f[12 + p] - sy[i] * sy[j] * Ninv;
        }
        for (int i = 0; i < 3; ++i)
            for (int j = 0; j < 3; ++j)
                Sxy[i * 3 + j] = (double)f[18 + i * 3 + j] - sx[i] * sy[j] * Ninv;

        double dot = 0.0;
        for (int p = 0; p < 3; ++p)
            dot += (double)f[27 + p] * Sx[p] + (double)f[33 + p] * Sy[p];
        for (int p = 3; p < 6; ++p)
            dot += 2.0 * ((double)f[27 + p] * Sx[p] + (double)f[33 + p] * Sy[p]);
        double cr = 0.0;
        for (int q = 0; q < 9; ++q) cr += (double)f[39 + q] * Sxy[q];
        dot -= 2.0 * cr;

        dots[tid] = dot;
    }
    __syncthreads();

    if (tid == 0) {
        const double denom = (double)BATCH * (double)NPTS * (double)NPTS * 3.0;
        double total = dots[0] + dots[1] + dots[2] + dots[3];
        out[0] = (float)(total / denom);
    }
}

extern "C" void kernel_launch(void* const* d_in, const int* in_sizes, int n_in,
                              void* d_out, int out_size, void* d_ws, size_t ws_size,
                              hipStream_t stream) {
    const float* x  = (const float*)d_in[0];
    const float* Rx = (const float*)d_in[1];
    const float* y  = (const float*)d_in[2];
    const float* Ry = (const float*)d_in[3];
    float* out = (float*)d_out;

    fape_onepass_kernel<<<1, BLK, 0, stream>>>(x, Rx, y, Ry, out);
}

// Round 3
// 16.344 us; speedup vs baseline: 3.5615x; 3.5615x over previous
//
#include <hip/hip_runtime.h>

// Problem constants (from reference setup_inputs): B=4, N=2048, d=3.
#define BATCH 4
#define NPTS  2048
#define TPB   256
#define BPB   8                   // blocks per batch (8*256 = 2048 -> 1 point/thread)
#define NBLK  (BATCH * BPB)       // 32 blocks total
#define NACC  48

// acc layout (48 floats):
//  [0:3) sx  [3:6) sy  [6:12) sxx(sym6)  [12:18) syy(sym6)  [18:27) sxy(9)
//  [27:33) A=sum RxRx^T(sym6)  [33:39) B=sum RyRy^T(sym6)  [39:48) C=sum RxRy^T(9)

__device__ float g_partial[NBLK][NACC];
__device__ int   g_ticket = 0;     // module-load init 0; last block resets to 0 each call

__global__ __launch_bounds__(TPB)
void fape_single_kernel(const float* __restrict__ x,
                        const float* __restrict__ Rx,
                        const float* __restrict__ y,
                        const float* __restrict__ Ry,
                        float* __restrict__ out)
{
    const int blk = blockIdx.x;
    const int b   = blk >> 3;      // batch 0..3
    const int kb  = blk & 7;       // sub-block within batch
    const int tid = threadIdx.x;
    const int n   = kb * TPB + tid;   // point index, lane-consecutive

    const float* __restrict__ xb  = x  + (size_t)b * NPTS * 3 + (size_t)n * 3;
    const float* __restrict__ yb  = y  + (size_t)b * NPTS * 3 + (size_t)n * 3;
    const float* __restrict__ rxb = Rx + (size_t)b * NPTS * 9 + (size_t)n * 9;
    const float* __restrict__ ryb = Ry + (size_t)b * NPTS * 9 + (size_t)n * 9;

    const int pi[6] = {0, 1, 2, 0, 0, 1};
    const int pj[6] = {0, 1, 2, 1, 2, 2};

    float xv[3], yv[3], rx[9], ry[9];
#pragma unroll
    for (int i = 0; i < 3; ++i) { xv[i] = xb[i]; yv[i] = yb[i]; }
#pragma unroll
    for (int i = 0; i < 9; ++i) { rx[i] = rxb[i]; ry[i] = ryb[i]; }

    float acc[NACC];
#pragma unroll
    for (int i = 0; i < 3; ++i) { acc[i] = xv[i]; acc[3 + i] = yv[i]; }
#pragma unroll
    for (int p = 0; p < 6; ++p) {
        const int i = pi[p], j = pj[p];
        acc[6  + p] = xv[i] * xv[j];
        acc[12 + p] = yv[i] * yv[j];
        float a = 0.f, bb = 0.f;
#pragma unroll
        for (int m = 0; m < 3; ++m) {
            a  += rx[i * 3 + m] * rx[j * 3 + m];
            bb += ry[i * 3 + m] * ry[j * 3 + m];
        }
        acc[27 + p] = a;
        acc[33 + p] = bb;
    }
#pragma unroll
    for (int i = 0; i < 3; ++i) {
#pragma unroll
        for (int j = 0; j < 3; ++j) {
            acc[18 + i * 3 + j] = xv[i] * yv[j];
            float c = 0.f;
#pragma unroll
            for (int m = 0; m < 3; ++m) c += rx[i * 3 + m] * ry[j * 3 + m];
            acc[39 + i * 3 + j] = c;
        }
    }

    // wave-64 shuffle reduction
#pragma unroll
    for (int off = 32; off > 0; off >>= 1) {
#pragma unroll
        for (int q = 0; q < NACC; ++q) acc[q] += __shfl_down(acc[q], off, 64);
    }

    // cross-wave reduction (4 waves/block)
    __shared__ float red[TPB / 64][NACC];
    const int wave = tid >> 6, lane = tid & 63;
    if (lane == 0) {
#pragma unroll
        for (int q = 0; q < NACC; ++q) red[wave][q] = acc[q];
    }
    __syncthreads();

    if (tid < NACC) {
        g_partial[blk][tid] = red[0][tid] + red[1][tid] + red[2][tid] + red[3][tid];
    }
    __threadfence();   // release: make partial stores device-visible
    __syncthreads();   // ensure storers' fences precede the ticket bump

    __shared__ int slast;
    if (tid == 0) {
        const int old = atomicAdd(&g_ticket, 1);
        slast = (old == NBLK - 1);
    }
    __syncthreads();
    if (!slast) return;

    // ---- last block: deterministic fixed-order finalize ----
    __threadfence();   // acquire
    volatile const float* vp = &g_partial[0][0];

    __shared__ float fin[BATCH][NACC];
    if (tid < BATCH * NACC) {
        const int bb = tid / NACC, q = tid % NACC;
        float s = 0.f;
#pragma unroll
        for (int k = 0; k < BPB; ++k) s += vp[(bb * BPB + k) * NACC + q];
        fin[bb][q] = s;
    }
    __syncthreads();

    __shared__ double dots[BATCH];
    if (tid < BATCH) {
        const float* f = fin[tid];
        const double Ninv = 1.0 / (double)NPTS;
        double sx[3], sy[3];
        for (int i = 0; i < 3; ++i) { sx[i] = f[0 + i]; sy[i] = f[3 + i]; }

        double Sx[6], Sy[6], Sxy[9];
        for (int p = 0; p < 6; ++p) {
            const int i = pi[p], j = pj[p];
            Sx[p] = (double)f[6  + p] - sx[i] * sx[j] * Ninv;
            Sy[p] = (double)f[12 + p] - sy[i] * sy[j] * Ninv;
        }
        for (int i = 0; i < 3; ++i)
            for (int j = 0; j < 3; ++j)
                Sxy[i * 3 + j] = (double)f[18 + i * 3 + j] - sx[i] * sy[j] * Ninv;

        double dot = 0.0;
        for (int p = 0; p < 3; ++p)
            dot += (double)f[27 + p] * Sx[p] + (double)f[33 + p] * Sy[p];
        for (int p = 3; p < 6; ++p)
            dot += 2.0 * ((double)f[27 + p] * Sx[p] + (double)f[33 + p] * Sy[p]);
        double cr = 0.0;
        for (int q = 0; q < 9; ++q) cr += (double)f[39 + q] * Sxy[q];
        dot -= 2.0 * cr;

        dots[tid] = dot;
    }
    __syncthreads();

    if (tid == 0) {
        const double denom = (double)BATCH * (double)NPTS * (double)NPTS * 3.0;
        out[0] = (float)((dots[0] + dots[1] + dots[2] + dots[3]) / denom);
        g_ticket = 0;          // restore for next (graph-replayed) launch
        __threadfence();
    }
}

extern "C" void kernel_launch(void* const* d_in, const int* in_sizes, int n_in,
                              void* d_out, int out_size, void* d_ws, size_t ws_size,
                              hipStream_t stream) {
    const float* x  = (const float*)d_in[0];
    const float* Rx = (const float*)d_in[1];
    const float* y  = (const float*)d_in[2];
    const float* Ry = (const float*)d_in[3];
    float* out = (float*)d_out;

    fape_single_kernel<<<NBLK, TPB, 0, stream>>>(x, Rx, y, Ry, out);
}